// Round 20
// baseline (170.765 us; speedup 1.0000x reference)
//
#include <hip/hip_runtime.h>
#include <hip/hip_fp8.h>
#include <stdint.h>

// SAGE_876173328847: 2-layer bipartite SAGEConv (mean agg) + log_softmax.
// N0=200000, N1=100000, N2=20000, E1=1.6M, E2=320K, D_IN=128, D_H=256, D_OUT=64.
//
// R1: atomic scatter -> CSR build + gather (3309 -> 667 us).
// R2/R3: bf16 + MFMA (-> 547). R4: fused mega, h1 in LDS (-> 472).
// R7: scan-based multi-split CSR, zero global atomics (-> 366).
// R8: spill-free mega (-> 347). R9: launch fusion (-> 285).
// R11: 32x32x16 fused mega (-> 264). R12: fragment-order W (-> 212).
// R13-15: gather tuning; line-service-bound (-> ~192).
// R16: fp8 e4m3 gather path (-> 180). R17/18: mega fp8 direct path (-> 173.5).
// R19: CSR chain 6 -> 4 launches (-> 169.8).
// R20: mega W-staging pipelined: 32KB ping-pong quarters, issue-early/
//      write-late (stage loads overlap MFMA), w2 staged in two pipelined
//      halves, setprio around MFMA. Same math, same barrier count.

#define CN0 200000
#define CN1 100000
#define CN2 20000
#define CE1 1600000
#define CE2 320000
#define CD_IN 128
#define CD_H 256
#define CD_OUT 64

// multi-split geometry: bucket = dst >> 9 (512 dsts per bucket)
#define NBK1 196          // ceil(N1/512)
#define NBK2 40           // ceil(N2/512)
#define G1 256
#define G2 64
#define CHUNK1 6250       // E1 / G1
#define CHUNK2 5000       // E2 / G2

typedef __bf16 bf16x8 __attribute__((ext_vector_type(8)));
typedef float f32x2 __attribute__((ext_vector_type(2)));
typedef float f32x4 __attribute__((ext_vector_type(4)));
typedef float f32x16 __attribute__((ext_vector_type(16)));
typedef uint16_t u16x4 __attribute__((ext_vector_type(4)));

__device__ inline uint16_t f2bf(float f) {
  uint32_t u = __float_as_uint(f);
  return (uint16_t)((u + 0x7fffu + ((u >> 16) & 1u)) >> 16);
}
__device__ inline float blo(uint32_t v) { return __uint_as_float(v << 16); }
__device__ inline float bhi(uint32_t v) { return __uint_as_float(v & 0xffff0000u); }

// ---- fp8 (OCP e4m3) helpers ----
__device__ inline uint32_t f32x4_to_fp8x4(float a, float b, float c, float d) {
#if __has_builtin(__builtin_amdgcn_cvt_pk_fp8_f32)
  uint32_t pk = (uint32_t)__builtin_amdgcn_cvt_pk_fp8_f32(a, b, 0, false);
  pk = (uint32_t)__builtin_amdgcn_cvt_pk_fp8_f32(c, d, (int)pk, true);
  return pk;
#else
  __hip_fp8_e4m3 e0(a), e1(b), e2(c), e3(d);
  return (uint32_t)e0.__x | ((uint32_t)e1.__x << 8) |
         ((uint32_t)e2.__x << 16) | ((uint32_t)e3.__x << 24);
#endif
}

__device__ inline float fp8_one(uint32_t b) {   // fallback scalar decode
  uint32_t s = (b >> 7) & 1u, e = (b >> 3) & 15u, m = b & 7u;
  float f = (e == 0) ? (float)m * 0.001953125f
                     : __uint_as_float(((e + 120u) << 23) | (m << 20));
  return s ? -f : f;
}

__device__ inline void fp8x4_dec(uint32_t w, float& p0, float& p1,
                                 float& p2, float& p3) {
#if __has_builtin(__builtin_amdgcn_cvt_pk_f32_fp8)
  f32x2 lo = __builtin_amdgcn_cvt_pk_f32_fp8(w, false);
  f32x2 hi = __builtin_amdgcn_cvt_pk_f32_fp8(w, true);
  p0 = lo[0]; p1 = lo[1]; p2 = hi[0]; p3 = hi[1];
#else
  p0 = fp8_one(w & 0xffu);
  p1 = fp8_one((w >> 8) & 0xffu);
  p2 = fp8_one((w >> 16) & 0xffu);
  p3 = fp8_one((w >> 24) & 0xffu);
#endif
}

__device__ inline void fp8x4_acc(uint32_t w, float& p0, float& p1,
                                 float& p2, float& p3) {
  float q0, q1, q2, q3;
  fp8x4_dec(w, q0, q1, q2, q3);
  p0 += q0; p1 += q1; p2 += q2; p3 += q3;
}

__device__ inline bf16x8 fp8x8_to_bf16x8(uint2 v) {
  float f[8];
  fp8x4_dec(v.x, f[0], f[1], f[2], f[3]);
  fp8x4_dec(v.y, f[4], f[5], f[6], f[7]);
  uint16_t o[8];
#pragma unroll
  for (int e = 0; e < 8; ++e) o[e] = f2bf(f[e]);
  return *reinterpret_cast<bf16x8*>(o);
}

// ---- fused: x->fp8 (12500 blk) + weight frags (48) + csr_count (320) ----
__global__ __launch_bounds__(256) void cvt_count(
    const float* __restrict__ x, const float* __restrict__ Wl1,
    const float* __restrict__ Wr1, const float* __restrict__ Wl2,
    const float* __restrict__ Wr2, const int* __restrict__ dst1,
    const int* __restrict__ dst2, uint32_t* __restrict__ x_fp8,
    uint16_t* __restrict__ wfragG, uint16_t* __restrict__ w2fragG,
    int* __restrict__ H1, int* __restrict__ H2) {
  __shared__ int hist[256];
  int blk = blockIdx.x;
  if (blk < 12500) {
    int i = blk * 256 + threadIdx.x;      // < 3,200,000 (each = 2 float4s)
    const float4* xp = reinterpret_cast<const float4*>(x);
    float4 v0 = xp[2 * i];
    float4 v1 = xp[2 * i + 1];
    uint2 o;
    o.x = f32x4_to_fp8x4(v0.x, v0.y, v0.z, v0.w);
    o.y = f32x4_to_fp8x4(v1.x, v1.y, v1.z, v1.w);
    reinterpret_cast<uint2*>(x_fp8)[i] = o;
    return;
  }
  if (blk < 12548) {
    int c = (blk - 12500) * 256 + threadIdx.x;   // 0..12287
    uint16_t o[8];
    if (c < 8192) {
      int lane = c & 63, t = (c >> 6) & 15, n = c >> 10;
      int row = n * 32 + (lane & 31);
      int kk = t * 16 + (lane >> 5) * 8;
      const float* srcp = (kk < 128) ? (Wl1 + (size_t)row * 128 + kk)
                                     : (Wr1 + (size_t)row * 128 + (kk - 128));
#pragma unroll
      for (int e = 0; e < 8; ++e) o[e] = f2bf(srcp[e]);
      *reinterpret_cast<int4*>(wfragG + (size_t)c * 8) = *reinterpret_cast<int4*>(o);
    } else {
      int cc = c - 8192;                    // 0..4095
      int lane = cc & 63, tt = (cc >> 6) & 15, j = cc >> 10;
      int row = j * 32 + (lane & 31);
      int kk = tt * 16 + (lane >> 5) * 8;
      const float* srcp = (row < 64) ? (Wl2 + (size_t)row * 256 + kk)
                                     : (Wr2 + (size_t)(row - 64) * 256 + kk);
#pragma unroll
      for (int e = 0; e < 8; ++e) o[e] = f2bf(srcp[e]);
      *reinterpret_cast<int4*>(w2fragG + (size_t)cc * 8) = *reinterpret_cast<int4*>(o);
    }
    return;
  }
  // ---- histogram chunk ----
  int g = blk - 12548, t = threadIdx.x;
  const int* dst; int* H; int E, nb, chunk;
  if (g < G1) { dst = dst1; H = H1; E = CE1; nb = NBK1; chunk = CHUNK1; }
  else { g -= G1; dst = dst2; H = H2; E = CE2; nb = NBK2; chunk = CHUNK2; }
  hist[t] = 0;
  __syncthreads();
  int e0 = g * chunk, e1 = min(e0 + chunk, E);
  for (int e = e0 + t; e < e1; e += 256) atomicAdd(&hist[dst[e] >> 9], 1);
  __syncthreads();
  if (t < nb) H[g * nb + t] = hist[t];
}

// ---------------- dual-layer scan-based multi-split ----------------
__global__ __launch_bounds__(256) void csr_scan(
    int* __restrict__ H1, int* __restrict__ H2,
    int* __restrict__ T1, int* __restrict__ T2) {
  __shared__ int sm[256];
  int b = blockIdx.x, t = threadIdx.x;
  int* H; int* T; int nb, G;
  if (b < NBK1) { H = H1; T = T1; nb = NBK1; G = G1; }
  else { b -= NBK1; H = H2; T = T2; nb = NBK2; G = G2; }
  int v = (t < G) ? H[t * nb + b] : 0;
  sm[t] = v;
  __syncthreads();
#pragma unroll
  for (int off = 1; off < 256; off <<= 1) {
    int u = (t >= off) ? sm[t - off] : 0;
    __syncthreads();
    sm[t] += u;
    __syncthreads();
  }
  if (t < G) H[t * nb + b] = sm[t] - v;  // exclusive over chunks
  if (t == 255) T[b] = sm[255];          // bucket total (= edges in bucket)
}

// place: Bb computed per-block via local LDS scan of T
__global__ __launch_bounds__(256) void csr_place(
    const int* __restrict__ src1, const int* __restrict__ dst1,
    const int* __restrict__ src2, const int* __restrict__ dst2,
    const int* __restrict__ H1, const int* __restrict__ H2,
    const int* __restrict__ T1, const int* __restrict__ T2,
    uint32_t* __restrict__ pairs1, uint32_t* __restrict__ pairs2) {
  __shared__ int curs[256];
  __shared__ int sm[256];
  int g = blockIdx.x, t = threadIdx.x;
  const int* src; const int* dst; const int* H; const int* T;
  uint32_t* pairs; int E, nb, chunk;
  if (g < G1) { src = src1; dst = dst1; H = H1; T = T1; pairs = pairs1;
                E = CE1; nb = NBK1; chunk = CHUNK1; }
  else { g -= G1; src = src2; dst = dst2; H = H2; T = T2; pairs = pairs2;
         E = CE2; nb = NBK2; chunk = CHUNK2; }
  int v = (t < nb) ? T[t] : 0;
  sm[t] = v;
  __syncthreads();
#pragma unroll
  for (int off = 1; off < 256; off <<= 1) {
    int u = (t >= off) ? sm[t - off] : 0;
    __syncthreads();
    sm[t] += u;
    __syncthreads();
  }
  if (t < nb) curs[t] = (sm[t] - v) + H[g * nb + t];
  __syncthreads();
  int e0 = g * chunk, e1 = min(e0 + chunk, E);
  for (int e = e0 + t; e < e1; e += 256) {
    int d = dst[e];
    int b = d >> 9;
    int p = atomicAdd(&curs[b], 1);
    pairs[p] = (uint32_t)src[e] | ((uint32_t)(d & 511) << 18);
  }
}

// bdeg+scan: s0 via tree reduction over T; writes deg + R (bucket-local)
__global__ __launch_bounds__(256) void csr_bdeg_scan(
    const uint32_t* __restrict__ pairs1, const uint32_t* __restrict__ pairs2,
    const int* __restrict__ T1, const int* __restrict__ T2,
    int* __restrict__ deg1, int* __restrict__ deg2,
    int* __restrict__ R1, int* __restrict__ R2) {
  __shared__ int cnt[512];
  __shared__ int sm[256];
  int b = blockIdx.x, t = threadIdx.x;
  const uint32_t* pairs; const int* T;
  int* deg; int* R; int ndst;
  if (b < NBK1) { pairs = pairs1; T = T1; deg = deg1; R = R1; ndst = CN1; }
  else { b -= NBK1; pairs = pairs2; T = T2; deg = deg2; R = R2; ndst = CN2; }
  cnt[t] = 0;
  cnt[t + 256] = 0;
  sm[t] = (t < b) ? T[t] : 0;
  __syncthreads();
#pragma unroll
  for (int off = 128; off > 0; off >>= 1) {
    if (t < off) sm[t] += sm[t + off];
    __syncthreads();
  }
  int s0 = sm[0];
  int n = T[b];
  __syncthreads();
  for (int i = t; i < n; i += 256) atomicAdd(&cnt[pairs[s0 + i] >> 18], 1);
  __syncthreads();
  int d0 = b << 9;
  int a = cnt[2 * t], c = cnt[2 * t + 1];
  int i0 = d0 + 2 * t, i1 = d0 + 2 * t + 1;
  if (i0 < ndst) deg[i0] = a;
  if (i1 < ndst) deg[i1] = c;
  int s = a + c;
  sm[t] = s;
  __syncthreads();
#pragma unroll
  for (int off = 1; off < 256; off <<= 1) {
    int u = (t >= off) ? sm[t - off] : 0;
    __syncthreads();
    sm[t] += u;
    __syncthreads();
  }
  int excl = sm[t] - s;
  if (i0 < ndst) R[i0] = excl;
  if (i1 < ndst) R[i1] = excl + a;
}

// bplace: s0 via reduction over T; absolutizes R
__global__ __launch_bounds__(256) void csr_bplace(
    const uint32_t* __restrict__ pairs1, const uint32_t* __restrict__ pairs2,
    const int* __restrict__ T1, const int* __restrict__ T2,
    int* __restrict__ R1, int* __restrict__ R2,
    int* __restrict__ esrc1, int* __restrict__ esrc2) {
  __shared__ int cnt[512];
  __shared__ int sm[256];
  int b = blockIdx.x, t = threadIdx.x;
  const uint32_t* pairs; const int* T;
  int* R; int* esrc; int ndst;
  if (b < NBK1) { pairs = pairs1; T = T1; R = R1; esrc = esrc1; ndst = CN1; }
  else { b -= NBK1; pairs = pairs2; T = T2; R = R2; esrc = esrc2; ndst = CN2; }
  sm[t] = (t < b) ? T[t] : 0;
  __syncthreads();
#pragma unroll
  for (int off = 128; off > 0; off >>= 1) {
    if (t < off) sm[t] += sm[t + off];
    __syncthreads();
  }
  int s0 = sm[0];
  int n = T[b];
  __syncthreads();
  int d0 = b << 9;
#pragma unroll
  for (int j = 0; j < 2; ++j) {
    int dd = d0 + t + j * 256;
    if (dd < ndst) {
      int r = R[dd] + s0;
      cnt[t + j * 256] = r;
      R[dd] = r;
    } else {
      cnt[t + j * 256] = 0;
    }
  }
  __syncthreads();
  for (int i = t; i < n; i += 256) {
    uint32_t pk = pairs[s0 + i];
    int p = atomicAdd(&cnt[pk >> 18], 1);
    esrc[p] = (int)(pk & 0x3FFFFu);
  }
}

// ------- gather-mean layer 1 (fp8 rows, 128B): one dst per WAVE -------
__global__ __launch_bounds__(256) void sage_gather1(
    const uint32_t* __restrict__ xf8, const int* __restrict__ esrc,
    const int* __restrict__ R, const int* __restrict__ deg,
    uint16_t* __restrict__ agg) {
  const int d = __builtin_amdgcn_readfirstlane(blockIdx.x * 4 + (threadIdx.x >> 6));
  const int lane = threadIdx.x & 63;
  const int cc = lane & 15;    // 8-byte chunk within row (cols 8cc..8cc+7)
  const int h = lane >> 4;     // 0..3 edge subgroup
  const int start = __builtin_amdgcn_readfirstlane(R[d]);
  const int n = __builtin_amdgcn_readfirstlane(deg[d]);
  const uint2* xw = reinterpret_cast<const uint2*>(xf8);   // row = 16 uint2
  float a0 = 0.f, a1 = 0.f, a2 = 0.f, a3 = 0.f;
  float a4 = 0.f, a5 = 0.f, a6 = 0.f, a7 = 0.f;
  float c0 = 0.f, c1 = 0.f, c2 = 0.f, c3 = 0.f;
  float c4 = 0.f, c5 = 0.f, c6 = 0.f, c7 = 0.f;
  int i = 0;
  for (; i + 16 <= n; i += 16) {
    int s0 = esrc[start + i + h];
    int s1 = esrc[start + i + 4 + h];
    int s2 = esrc[start + i + 8 + h];
    int s3 = esrc[start + i + 12 + h];
    uint2 v0 = xw[(uint32_t)s0 * 16u + cc];
    uint2 v1 = xw[(uint32_t)s1 * 16u + cc];
    uint2 v2 = xw[(uint32_t)s2 * 16u + cc];
    uint2 v3 = xw[(uint32_t)s3 * 16u + cc];
    fp8x4_acc(v0.x, a0, a1, a2, a3);
    fp8x4_acc(v0.y, a4, a5, a6, a7);
    fp8x4_acc(v1.x, a0, a1, a2, a3);
    fp8x4_acc(v1.y, a4, a5, a6, a7);
    fp8x4_acc(v2.x, c0, c1, c2, c3);
    fp8x4_acc(v2.y, c4, c5, c6, c7);
    fp8x4_acc(v3.x, c0, c1, c2, c3);
    fp8x4_acc(v3.y, c4, c5, c6, c7);
  }
  for (; i + 4 <= n; i += 4) {
    int s0 = esrc[start + i + h];
    uint2 v = xw[(uint32_t)s0 * 16u + cc];
    fp8x4_acc(v.x, a0, a1, a2, a3);
    fp8x4_acc(v.y, a4, a5, a6, a7);
  }
  if (i < n && h < n - i) {
    int s0 = esrc[start + i + h];
    uint2 v = xw[(uint32_t)s0 * 16u + cc];
    fp8x4_acc(v.x, a0, a1, a2, a3);
    fp8x4_acc(v.y, a4, a5, a6, a7);
  }
  a0 += c0; a1 += c1; a2 += c2; a3 += c3;
  a4 += c4; a5 += c5; a6 += c6; a7 += c7;
  a0 += __shfl_xor(a0, 16); a0 += __shfl_xor(a0, 32);
  a1 += __shfl_xor(a1, 16); a1 += __shfl_xor(a1, 32);
  a2 += __shfl_xor(a2, 16); a2 += __shfl_xor(a2, 32);
  a3 += __shfl_xor(a3, 16); a3 += __shfl_xor(a3, 32);
  a4 += __shfl_xor(a4, 16); a4 += __shfl_xor(a4, 32);
  a5 += __shfl_xor(a5, 16); a5 += __shfl_xor(a5, 32);
  a6 += __shfl_xor(a6, 16); a6 += __shfl_xor(a6, 32);
  a7 += __shfl_xor(a7, 16); a7 += __shfl_xor(a7, 32);
  if (lane < 16) {
    float inv = 1.0f / fmaxf((float)n, 1.0f);
    uint4 o;
    o.x = (uint32_t)f2bf(a0 * inv) | ((uint32_t)f2bf(a1 * inv) << 16);
    o.y = (uint32_t)f2bf(a2 * inv) | ((uint32_t)f2bf(a3 * inv) << 16);
    o.z = (uint32_t)f2bf(a4 * inv) | ((uint32_t)f2bf(a5 * inv) << 16);
    o.w = (uint32_t)f2bf(a6 * inv) | ((uint32_t)f2bf(a7 * inv) << 16);
    reinterpret_cast<uint4*>(agg)[(size_t)d * 16 + cc] = o;
  }
}

// ------- FUSED gather-mean layer 2 + log_softmax finalize -------
__global__ __launch_bounds__(256) void sage_gather2_fin(
    const uint16_t* __restrict__ t2, const int* __restrict__ esrc,
    const int* __restrict__ R, const int* __restrict__ deg,
    const float* __restrict__ b2, float* __restrict__ out) {
  int d = blockIdx.x * 8 + (threadIdx.x >> 5);
  int c = threadIdx.x & 31;
  if (d >= CN2) return;
  int start = R[d], n = deg[d];
  const uint32_t* tw = reinterpret_cast<const uint32_t*>(t2);
  float a0 = 0.f, a1 = 0.f, b0 = 0.f, b1 = 0.f;
  int i = 0;
  for (; i + 8 <= n; i += 8) {
    int s0 = esrc[start + i + 0], s1 = esrc[start + i + 1];
    int s2 = esrc[start + i + 2], s3 = esrc[start + i + 3];
    int s4 = esrc[start + i + 4], s5 = esrc[start + i + 5];
    int s6 = esrc[start + i + 6], s7 = esrc[start + i + 7];
    uint32_t v0 = tw[(size_t)s0 * 32 + c], v1 = tw[(size_t)s1 * 32 + c];
    uint32_t v2 = tw[(size_t)s2 * 32 + c], v3 = tw[(size_t)s3 * 32 + c];
    uint32_t v4 = tw[(size_t)s4 * 32 + c], v5 = tw[(size_t)s5 * 32 + c];
    uint32_t v6 = tw[(size_t)s6 * 32 + c], v7 = tw[(size_t)s7 * 32 + c];
    a0 += (blo(v0) + blo(v1)) + (blo(v2) + blo(v3));
    b0 += (blo(v4) + blo(v5)) + (blo(v6) + blo(v7));
    a1 += (bhi(v0) + bhi(v1)) + (bhi(v2) + bhi(v3));
    b1 += (bhi(v4) + bhi(v5)) + (bhi(v6) + bhi(v7));
  }
  for (; i + 2 <= n; i += 2) {
    int s0 = esrc[start + i + 0], s1 = esrc[start + i + 1];
    uint32_t v0 = tw[(size_t)s0 * 32 + c], v1 = tw[(size_t)s1 * 32 + c];
    a0 += blo(v0) + blo(v1);
    a1 += bhi(v0) + bhi(v1);
  }
  if (i < n) {
    uint32_t v = tw[(size_t)esrc[start + i] * 32 + c];
    a0 += blo(v);
    a1 += bhi(v);
  }
  a0 += b0; a1 += b1;
  float inv = 1.0f / fmaxf((float)n, 1.0f);

  float2 ov = reinterpret_cast<const float2*>(out)[(size_t)d * 32 + c];
  float2 bb = reinterpret_cast<const float2*>(b2)[c];
  float v0 = ov.x + a0 * inv + bb.x;
  float v1 = ov.y + a1 * inv + bb.y;
  float m = fmaxf(v0, v1);
#pragma unroll
  for (int off = 16; off > 0; off >>= 1) m = fmaxf(m, __shfl_xor(m, off));
  float s = expf(v0 - m) + expf(v1 - m);
#pragma unroll
  for (int off = 16; off > 0; off >>= 1) s += __shfl_xor(s, off);
  float lg = logf(s);
  float2 r;
  r.x = v0 - m - lg;
  r.y = v1 - m - lg;
  reinterpret_cast<float2*>(out)[(size_t)d * 32 + c] = r;
}

// ---------------- MEGA kernel (R20: pipelined W staging) ----------------
// wfrag = two 32KB ping-pong buffers, each = one W1 quarter (2 n-groups).
// Per quarter: issue next-quarter loads -> compute 2 n-groups (hides L2
// latency) -> ds_write staged regs -> barrier. w2 staged the same way.
__global__ __launch_bounds__(256, 2) void sage_mega(
    const uint16_t* __restrict__ agg, const uint32_t* __restrict__ xf8,
    const uint16_t* __restrict__ wfragG, const uint16_t* __restrict__ w2fragG,
    const float* __restrict__ bias, uint16_t* __restrict__ t2,
    float* __restrict__ outp) {
  __shared__ uint16_t wfrag[32768];       // buf0 = [0,16384), buf1 = [16384,32768)
  __shared__ uint16_t h1t[4 * 32 * 40];   // per-wave 32x40 transpose tile
  const int tid = threadIdx.x;
  const int w = tid >> 6;
  const int lane = tid & 63;
  const int lcol = lane & 31;             // A-row / B-col / C-col
  const int hi = lane >> 5;               // k-half (frags) / row +4 (C)
  const int row0 = blockIdx.x * 128 + w * 32;
  uint16_t* hw = &h1t[w * (32 * 40)];
  uint16_t* buf0 = wfrag;
  uint16_t* buf1 = wfrag + 16384;

  // A fragments: 16 k-tiles of K=16 from [agg (bf16) | x (fp8 dequant)]
  int arow = row0 + lcol;
  arow = arow < CN1 ? arow : CN1 - 1;
  bf16x8 afr[16];
#pragma unroll
  for (int t = 0; t < 8; ++t) {
    afr[t] = *reinterpret_cast<const bf16x8*>(
        agg + (size_t)arow * CD_IN + t * 16 + hi * 8);
  }
#pragma unroll
  for (int t = 8; t < 16; ++t) {
    const int koff = t * 16 - 128;
    uint2 v = reinterpret_cast<const uint2*>(xf8)[
        (uint32_t)arow * 16u + (uint32_t)(koff >> 3) + (uint32_t)hi];
    afr[t] = fp8x8_to_bf16x8(v);
  }

  const bool do_out = (row0 < CN2);
  bf16x8 a2[16];
  int4 st[8];

  // prologue: stage quarter 0 (W1 chunks 0..31) into buf0
#pragma unroll
  for (int i = 0; i < 8; ++i) {
    int cc = i * 4 + w;
    st[i] = *reinterpret_cast<const int4*>(wfragG + (size_t)cc * 512 + lane * 8);
  }
#pragma unroll
  for (int i = 0; i < 8; ++i) {
    int cc = i * 4 + w;
    *reinterpret_cast<int4*>(&buf0[cc * 512 + lane * 8]) = st[i];
  }
  __syncthreads();

  // ---- phase 1: 4 quarters, ping-pong staged ----
#pragma unroll
  for (int q = 0; q < 4; ++q) {
    uint16_t* cur = (q & 1) ? buf1 : buf0;
    uint16_t* nxt = (q & 1) ? buf0 : buf1;
    // issue-early: next quarter's loads (q<3: W1; q==3: w2 first half)
    if (q < 3) {
#pragma unroll
      for (int i = 0; i < 8; ++i) {
        int cc = i * 4 + w;
        st[i] = *reinterpret_cast<const int4*>(
            wfragG + (size_t)((q + 1) * 32 + cc) * 512 + lane * 8);
      }
    } else {
#pragma unroll
      for (int i = 0; i < 8; ++i) {
        int cc = i * 4 + w;
        st[i] = *reinterpret_cast<const int4*>(
            w2fragG + (size_t)cc * 512 + lane * 8);
      }
    }
    // compute the quarter's 2 n-groups from cur
#pragma unroll
    for (int nq = 0; nq < 2; ++nq) {
      const int n = q * 2 + nq;
      const float bb = bias[n * 32 + lcol];
      f32x16 p0 = (f32x16)0.0f, p1 = (f32x16)0.0f;
      __builtin_amdgcn_s_setprio(1);
#pragma unroll
      for (int t = 0; t < 16; t += 2) {
        bf16x8 b0 = *reinterpret_cast<const bf16x8*>(
            &cur[((nq * 16 + t) * 64 + lane) * 8]);
        bf16x8 b1 = *reinterpret_cast<const bf16x8*>(
            &cur[((nq * 16 + t + 1) * 64 + lane) * 8]);
        p0 = __builtin_amdgcn_mfma_f32_32x32x16_bf16(afr[t], b0, p0, 0, 0, 0);
        p1 = __builtin_amdgcn_mfma_f32_32x32x16_bf16(afr[t + 1], b1, p1, 0, 0, 0);
      }
      __builtin_amdgcn_s_setprio(0);
      // bias + relu -> bf16 -> per-wave LDS transpose tile (C layout m74/m101)
#pragma unroll
      for (int r = 0; r < 16; ++r) {
        float v = fmaxf(p0[r] + p1[r] + bb, 0.0f);
        int R = (r & 3) + 8 * (r >> 2) + 4 * hi;
        hw[R * 40 + lcol] = f2bf(v);
      }
      a2[n * 2 + 0] = *reinterpret_cast<const bf16x8*>(&hw[lcol * 40 + hi * 8]);
      a2[n * 2 + 1] = *reinterpret_cast<const bf16x8*>(&hw[lcol * 40 + 16 + hi * 8]);
    }
    // write-late: staged regs -> nxt (q==3: w2 first half -> buf0 == nxt)
#pragma unroll
    for (int i = 0; i < 8; ++i) {
      int cc = i * 4 + w;
      *reinterpret_cast<int4*>(&nxt[cc * 512 + lane * 8]) = st[i];
    }
    __syncthreads();
  }

  // ---- phase 2 ----
  // buf0 holds w2 chunks 0..31 (j=0,1). Issue second half (j=2,3) now.
#pragma unroll
  for (int i = 0; i < 8; ++i) {
    int cc = i * 4 + w;
    st[i] = *reinterpret_cast<const int4*>(
        w2fragG + (size_t)(32 + cc) * 512 + lane * 8);
  }
  // jp=0: t2 cols from buf0 (local jA=0 -> chunks 0..15, jB=1 -> 16..31)
  {
    f32x16 aA = (f32x16)0.0f, aB = (f32x16)0.0f;
    __builtin_amdgcn_s_setprio(1);
#pragma unroll
    for (int s = 0; s < 8; ++s) {
      bf16x8 c0A = *reinterpret_cast<const bf16x8*>(
          &buf0[((0 * 16 + s * 2) * 64 + lane) * 8]);
      bf16x8 c1A = *reinterpret_cast<const bf16x8*>(
          &buf0[((0 * 16 + s * 2 + 1) * 64 + lane) * 8]);
      bf16x8 c0B = *reinterpret_cast<const bf16x8*>(
          &buf0[((1 * 16 + s * 2) * 64 + lane) * 8]);
      bf16x8 c1B = *reinterpret_cast<const bf16x8*>(
          &buf0[((1 * 16 + s * 2 + 1) * 64 + lane) * 8]);
      aA = __builtin_amdgcn_mfma_f32_32x32x16_bf16(a2[s * 2], c0A, aA, 0, 0, 0);
      aB = __builtin_amdgcn_mfma_f32_32x32x16_bf16(a2[s * 2], c0B, aB, 0, 0, 0);
      aA = __builtin_amdgcn_mfma_f32_32x32x16_bf16(a2[s * 2 + 1], c1A, aA, 0, 0, 0);
      aB = __builtin_amdgcn_mfma_f32_32x32x16_bf16(a2[s * 2 + 1], c1B, aB, 0, 0, 0);
    }
    __builtin_amdgcn_s_setprio(0);
#pragma unroll
    for (int r = 0; r < 16; ++r) {
      int R = (r & 3) + 8 * (r >> 2) + 4 * hi;
      int rg = row0 + R;
      if (rg < CN1) {
        t2[(size_t)rg * 64 + lcol] = f2bf(aA[r]);
        t2[(size_t)rg * 64 + 32 + lcol] = f2bf(aB[r]);
      }
    }
  }
  // write w2 second half -> buf1, sync
#pragma unroll
  for (int i = 0; i < 8; ++i) {
    int cc = i * 4 + w;
    *reinterpret_cast<int4*>(&buf1[cc * 512 + lane * 8]) = st[i];
  }
  __syncthreads();
  // jp=1: out cols from buf1 (local jA=0, jB=1 == global j=2,3)
  if (do_out) {
    f32x16 aA = (f32x16)0.0f, aB = (f32x16)0.0f;
    __builtin_amdgcn_s_setprio(1);
#pragma unroll
    for (int s = 0; s < 8; ++s) {
      bf16x8 c0A = *reinterpret_cast<const bf16x8*>(
          &buf1[((0 * 16 + s * 2) * 64 + lane) * 8]);
      bf16x8 c1A = *reinterpret_cast<const bf16x8*>(
          &buf1[((0 * 16 + s * 2 + 1) * 64 + lane) * 8]);
      bf16x8 c0B = *reinterpret_cast<const bf16x8*>(
          &buf1[((1 * 16 + s * 2) * 64 + lane) * 8]);
      bf16x8 c1B = *reinterpret_cast<const bf16x8*>(
          &buf1[((1 * 16 + s * 2 + 1) * 64 + lane) * 8]);
      aA = __builtin_amdgcn_mfma_f32_32x32x16_bf16(a2[s * 2], c0A, aA, 0, 0, 0);
      aB = __builtin_amdgcn_mfma_f32_32x32x16_bf16(a2[s * 2], c0B, aB, 0, 0, 0);
      aA = __builtin_amdgcn_mfma_f32_32x32x16_bf16(a2[s * 2 + 1], c1A, aA, 0, 0, 0);
      aB = __builtin_amdgcn_mfma_f32_32x32x16_bf16(a2[s * 2 + 1], c1B, aB, 0, 0, 0);
    }
    __builtin_amdgcn_s_setprio(0);
#pragma unroll
    for (int r = 0; r < 16; ++r) {
      int R = (r & 3) + 8 * (r >> 2) + 4 * hi;
      int rg = row0 + R;
      outp[(size_t)rg * 64 + lcol] = aA[r];
      outp[(size_t)rg * 64 + 32 + lcol] = aB[r];
    }
  }
}

extern "C" void kernel_launch(void* const* d_in, const int* in_sizes, int n_in,
                              void* d_out, int out_size, void* d_ws, size_t ws_size,
                              hipStream_t stream) {
  const float* x    = (const float*)d_in[0];
  const int* src1   = (const int*)d_in[1];
  const int* dst1   = (const int*)d_in[2];
  const int* src2   = (const int*)d_in[3];
  const int* dst2   = (const int*)d_in[4];
  const float* W_l1 = (const float*)d_in[5];
  const float* b_l1 = (const float*)d_in[6];
  const float* W_r1 = (const float*)d_in[7];
  const float* W_l2 = (const float*)d_in[8];
  const float* b_l2 = (const float*)d_in[9];
  const float* W_r2 = (const float*)d_in[10];
  float* out = (float*)d_out;
  char* base = (char*)d_ws;

  // ---- workspace layout (bytes), ~73 MB, lifetime-aliased ----
  uint32_t* x_fp8 = (uint32_t*)base;
  uint16_t* t2_bf = (uint16_t*)(base + 25600000);
  uint16_t* agg_bf= (uint16_t*)(base + 38400000);
  uint32_t* pairs1= (uint32_t*)(base + 38400000);          // alias (dead before gather1)
  uint32_t* pairs2= (uint32_t*)(base + 44800000);          // alias
  int* deg1 = (int*)(base + 64000000);                     // 400 KB
  int* R1   = (int*)(base + 64400000);                     // 400 KB
  int* esrc1= (int*)(base + 64800000);                     // 6.4 MB
  int* deg2 = (int*)(base + 71200000);                     // 80 KB
  int* R2   = (int*)(base + 71280000);                     // 80 KB
  int* esrc2= (int*)(base + 71360000);                     // 1.28 MB
  int* H1   = (int*)(base + 72640000);                     // 200,704 B
  int* H2   = (int*)(base + 72840704);                     // 10,240 B
  char* misc = base + 72850944;
  int* T1  = (int*)(misc);
  int* T2  = (int*)(misc + 2048);
  uint16_t* wfragG  = (uint16_t*)(misc + 6144);            // 128 KB (frag order)
  uint16_t* w2fragG = wfragG + 65536;                      // 64 KB (frag order)

  if (ws_size < 74000000u) return;

  // ---- fused convert (fp8 only) + weight frags + csr_count ----
  cvt_count<<<12868, 256, 0, stream>>>(x, W_l1, W_r1, W_l2, W_r2, dst1, dst2,
                                       x_fp8, wfragG, w2fragG, H1, H2);

  // ---- dual-layer CSR build (4 launches) ----
  csr_scan<<<NBK1 + NBK2, 256, 0, stream>>>(H1, H2, T1, T2);
  csr_place<<<G1 + G2, 256, 0, stream>>>(src1, dst1, src2, dst2, H1, H2,
                                         T1, T2, pairs1, pairs2);
  csr_bdeg_scan<<<NBK1 + NBK2, 256, 0, stream>>>(pairs1, pairs2, T1, T2,
                                                 deg1, deg2, R1, R2);
  csr_bplace<<<NBK1 + NBK2, 256, 0, stream>>>(pairs1, pairs2, T1, T2,
                                              R1, R2, esrc1, esrc2);

  // ---- gather1 (fp8) -> mega (pipelined W) -> fused gather2+finalize ----
  sage_gather1<<<(CN1 + 3) / 4, 256, 0, stream>>>(x_fp8, esrc1, R1, deg1, agg_bf);
  sage_mega<<<(CN1 + 127) / 128, 256, 0, stream>>>(
      agg_bf, x_fp8, wfragG, w2fragG, b_l1, t2_bf, out);
  sage_gather2_fin<<<(CN2 + 7) / 8, 256, 0, stream>>>(
      t2_bf, esrc2, R2, deg2, b_l2, out);
}